// Round 5
// baseline (1129.657 us; speedup 1.0000x reference)
//
#include <hip/hip_runtime.h>
#include <cstdint>
#include <cstddef>

#define CDIV(a,b) (((a)+(b)-1)/(b))

typedef __attribute__((ext_vector_type(8))) unsigned short ushort8v;
typedef __attribute__((ext_vector_type(8))) short short8v;
typedef __attribute__((ext_vector_type(4))) float f32x4;

__device__ __forceinline__ float bf2f(unsigned short u) {
  return __uint_as_float(((unsigned)u) << 16);
}
__device__ __forceinline__ unsigned short f2bf(float f) {
  unsigned u = __float_as_uint(f);
  unsigned r = (u + 0x7fff + ((u >> 16) & 1)) >> 16;
  return (unsigned short)r;
}

// ---------------- bucketed CSR build ----------------

__global__ __launch_bounds__(256) void k_bcount(const int* __restrict__ dst, int E,
                                                int* __restrict__ bucketCnt) {
  __shared__ int h[256];
  int t = threadIdx.x;
  h[t] = 0;
  __syncthreads();
  int e0 = blockIdx.x * 2048, e1 = min(e0 + 2048, E);
  for (int e = e0 + t; e < e1; e += 256) atomicAdd(&h[dst[e] >> 9], 1);
  __syncthreads();
  if (h[t]) atomicAdd(&bucketCnt[t], h[t]);
}

__global__ void k_bscan(const int* __restrict__ bucketCnt, int* __restrict__ bstart,
                        int* __restrict__ gcur, int* __restrict__ rowp, int n, int E,
                        double* __restrict__ gcsum) {
  __shared__ int sh[256];
  int t = threadIdx.x;
  if (t < 64) gcsum[t] = 0.0;   // zero attention accumulator for this graph
  int v = bucketCnt[t];
  sh[t] = v; __syncthreads();
  for (int o = 1; o < 256; o <<= 1) {
    int x = (t >= o) ? sh[t - o] : 0;
    __syncthreads();
    sh[t] += x;
    __syncthreads();
  }
  int ex = sh[t] - v;
  bstart[t] = ex;
  gcur[t] = ex;
  if (t == 255) { bstart[256] = E; rowp[n] = E; }
}

__global__ __launch_bounds__(256) void k_part(const int* __restrict__ src,
                                              const int* __restrict__ dst, int E,
                                              int* __restrict__ gcur, int2* __restrict__ part) {
  __shared__ int bcnt[256], bbase[256], bcur[256];
  int t = threadIdx.x;
  int e0 = blockIdx.x * 4096, e1 = min(e0 + 4096, E);
  bcnt[t] = 0;
  __syncthreads();
  for (int e = e0 + t; e < e1; e += 256) atomicAdd(&bcnt[dst[e] >> 9], 1);
  __syncthreads();
  bbase[t] = bcnt[t] ? atomicAdd(&gcur[t], bcnt[t]) : 0;
  bcur[t] = 0;
  __syncthreads();
  for (int e = e0 + t; e < e1; e += 256) {
    int d = dst[e], s = src[e];
    int b = d >> 9;
    int off = atomicAdd(&bcur[b], 1);
    part[bbase[b] + off] = make_int2(s, d);
  }
}

__global__ __launch_bounds__(256) void k_build(const int2* __restrict__ part,
                                               const int* __restrict__ bstart,
                                               int* __restrict__ rowp, int* __restrict__ col,
                                               float* __restrict__ dinv, int n) {
  __shared__ int cnt[512], off[512], tmp[256];
  int b = blockIdx.x;
  int lo = b << 9;
  if (lo >= n) return;
  int t = threadIdx.x;
  int s0 = bstart[b], s1 = bstart[b + 1];
  cnt[t] = 0; cnt[t + 256] = 0;
  __syncthreads();
  for (int e = s0 + t; e < s1; e += 256) atomicAdd(&cnt[part[e].y - lo], 1);
  __syncthreads();
  int a0 = cnt[2 * t], a1 = cnt[2 * t + 1];
  int ps = a0 + a1;
  tmp[t] = ps; __syncthreads();
  for (int o = 1; o < 256; o <<= 1) {
    int x = (t >= o) ? tmp[t - o] : 0;
    __syncthreads();
    tmp[t] += x;
    __syncthreads();
  }
  int ex = tmp[t] - ps;
  off[2 * t] = ex;
  off[2 * t + 1] = ex + a0;
  __syncthreads();
  for (int i = t; i < 512; i += 256) {
    int node = lo + i;
    if (node < n) {
      rowp[node] = s0 + off[i];
      dinv[node] = rsqrtf((float)(cnt[i] + 1));
    }
  }
  __syncthreads();
  for (int e = s0 + t; e < s1; e += 256) {
    int2 pr = part[e];
    int p = atomicAdd(&off[pr.y - lo], 1);
    col[s0 + p] = pr.x;
  }
}

// ---------------- f32 -> bf16 convert ----------------

__global__ void k_tobf(const float* __restrict__ in, unsigned short* __restrict__ out, int n8) {
  int i = blockIdx.x * blockDim.x + threadIdx.x;
  if (i < n8) {
    const float4* i4 = (const float4*)in;
    float4 a = i4[2 * i], b = i4[2 * i + 1];
    ushort8v r;
    r[0] = f2bf(a.x); r[1] = f2bf(a.y); r[2] = f2bf(a.z); r[3] = f2bf(a.w);
    r[4] = f2bf(b.x); r[5] = f2bf(b.y); r[6] = f2bf(b.z); r[7] = f2bf(b.w);
    ((ushort8v*)out)[i] = r;
  }
}

// ---- W prep: bf16, transposed to [n][k], chunk-swizzled LDS image ----

__global__ void k_wprep(const float* __restrict__ W, unsigned short* __restrict__ out,
                        int K, int DOUT) {
  int id = blockIdx.x * blockDim.x + threadIdx.x;   // id = k*DOUT + n
  if (id < K * DOUT) {
    int k = id / DOUT, n = id % DOUT;
    int CM = (K >> 3) - 1;
    out[n * K + (((k >> 3) + n) & CM) * 8 + (k & 7)] = f2bf(W[id]);
  }
}

// ---- fused aggregate + MFMA GEMM: C = relu(agg(X) @ W + b), bf16 out ----
// Block = 128 rows x full DOUT. Gather phase writes the swizzled LDS A-tile
// directly (same bf16 rounding point as the old agg->global->stage path).

template<int K, int DOUT, bool RELU>
__global__ __launch_bounds__(256) void k_aggemm(
    const unsigned short* __restrict__ X, const unsigned short* __restrict__ Wp,
    const float* __restrict__ bias, unsigned short* __restrict__ C,
    const int* __restrict__ rowp, const int* __restrict__ col,
    const float* __restrict__ dinv, int n) {
  constexpr int CPR = K / 8;
  constexpr int CM = CPR - 1;
  constexpr int NT = DOUT / 16;
  constexpr int NPB = 256 / CPR;
  __shared__ unsigned short As[128 * K];
  __shared__ unsigned short Ws[DOUT * K];
  int t = threadIdx.x;
  int blockM = blockIdx.x * 128;

  // stage W image
#pragma unroll
  for (int id = t; id < DOUT * CPR; id += 256)
    ((ushort8v*)Ws)[id] = ((const ushort8v*)Wp)[id];

  // gather + aggregate directly into swizzled LDS A-tile
  const ushort8v* x8 = (const ushort8v*)X;
  int g = t % CPR, sub = t / CPR;
#pragma unroll
  for (int pass = 0; pass < 128 / NPB; ++pass) {
    int r = pass * NPB + sub;
    int node = blockM + r;
    float acc[8];
#pragma unroll
    for (int j = 0; j < 8; ++j) acc[j] = 0.f;
    if (node < n) {
      float di = dinv[node];
      ushort8v xs = x8[(size_t)node * CPR + g];
#pragma unroll
      for (int j = 0; j < 8; ++j) acc[j] = di * bf2f(xs[j]);  // self loop
      int e = rowp[node], e1 = rowp[node + 1];
      for (; e + 4 <= e1; e += 4) {
        int s0 = col[e], s1 = col[e + 1], s2 = col[e + 2], s3 = col[e + 3];
        float w0 = dinv[s0], w1 = dinv[s1], w2 = dinv[s2], w3 = dinv[s3];
        ushort8v v0 = x8[(size_t)s0 * CPR + g];
        ushort8v v1 = x8[(size_t)s1 * CPR + g];
        ushort8v v2 = x8[(size_t)s2 * CPR + g];
        ushort8v v3 = x8[(size_t)s3 * CPR + g];
#pragma unroll
        for (int j = 0; j < 8; ++j) {
          acc[j] += w0 * bf2f(v0[j]);
          acc[j] += w1 * bf2f(v1[j]);
          acc[j] += w2 * bf2f(v2[j]);
          acc[j] += w3 * bf2f(v3[j]);
        }
      }
      for (; e < e1; ++e) {
        int s = col[e];
        float w = dinv[s];
        ushort8v v = x8[(size_t)s * CPR + g];
#pragma unroll
        for (int j = 0; j < 8; ++j) acc[j] += w * bf2f(v[j]);
      }
#pragma unroll
      for (int j = 0; j < 8; ++j) acc[j] *= di;
    }
    ushort8v o;
#pragma unroll
    for (int j = 0; j < 8; ++j) o[j] = f2bf(acc[j]);
    *(ushort8v*)&As[r * K + ((g + r) & CM) * 8] = o;
  }
  __syncthreads();

  // MFMA phase
  int lane = t & 63, wave = t >> 6;
  int m15 = lane & 15, quad = lane >> 4;
  f32x4 cacc[2][NT];
#pragma unroll
  for (int i = 0; i < 2; ++i)
#pragma unroll
    for (int j = 0; j < NT; ++j) cacc[i][j] = (f32x4){0.f, 0.f, 0.f, 0.f};

  int i0 = wave * 32 + m15;
  int i1 = i0 + 16;
#pragma unroll
  for (int kc = 0; kc < K; kc += 32) {
    int c0 = (kc >> 3) + quad;
    short8v a0 = *(const short8v*)&As[i0 * K + ((c0 + i0) & CM) * 8];
    short8v a1 = *(const short8v*)&As[i1 * K + ((c0 + i1) & CM) * 8];
    short8v b[NT];
#pragma unroll
    for (int nt = 0; nt < NT; ++nt) {
      int nn = nt * 16 + m15;
      b[nt] = *(const short8v*)&Ws[nn * K + ((c0 + nn) & CM) * 8];
    }
#pragma unroll
    for (int nt = 0; nt < NT; ++nt) {
      cacc[0][nt] = __builtin_amdgcn_mfma_f32_16x16x32_bf16(a0, b[nt], cacc[0][nt], 0, 0, 0);
      cacc[1][nt] = __builtin_amdgcn_mfma_f32_16x16x32_bf16(a1, b[nt], cacc[1][nt], 0, 0, 0);
    }
  }

#pragma unroll
  for (int rt = 0; rt < 2; ++rt) {
    int rbase = blockM + wave * 32 + rt * 16 + quad * 4;
#pragma unroll
    for (int nt = 0; nt < NT; ++nt) {
      int colg = nt * 16 + m15;
      float bv = bias ? bias[colg] : 0.f;
#pragma unroll
      for (int r = 0; r < 4; ++r) {
        int row = rbase + r;
        if (row < n) {
          float v = cacc[rt][nt][r] + bv;
          if (RELU) v = fmaxf(v, 0.f);
          C[(size_t)row * DOUT + colg] = f2bf(v);
        }
      }
    }
  }
}

// ---------------- plain MFMA GEMM (L2: 128->64, bf16 out) ----------------

template<int K, int DOUT, bool RELU>
__global__ __launch_bounds__(256) void k_mgemm(
    const unsigned short* __restrict__ A, const unsigned short* __restrict__ Wp,
    const float* __restrict__ bias, unsigned short* __restrict__ C, int n) {
  constexpr int CPR = K / 8;
  constexpr int CM = CPR - 1;
  constexpr int NT = DOUT / 16;
  __shared__ unsigned short As[128 * K];
  __shared__ unsigned short Ws[DOUT * K];
  int t = threadIdx.x;
  int blockM = blockIdx.x * 128;

#pragma unroll
  for (int id = t; id < 128 * CPR; id += 256) {
    int r = id / CPR, c = id % CPR;
    int grow = blockM + r;
    ushort8v v = {0, 0, 0, 0, 0, 0, 0, 0};
    if (grow < n) v = ((const ushort8v*)A)[(size_t)grow * CPR + c];
    *(ushort8v*)&As[r * K + ((c + r) & CM) * 8] = v;
  }
#pragma unroll
  for (int id = t; id < DOUT * CPR; id += 256) {
    ((ushort8v*)Ws)[id] = ((const ushort8v*)Wp)[id];
  }
  __syncthreads();

  int lane = t & 63, wave = t >> 6;
  int m15 = lane & 15, quad = lane >> 4;
  f32x4 acc[2][NT];
#pragma unroll
  for (int i = 0; i < 2; ++i)
#pragma unroll
    for (int j = 0; j < NT; ++j) acc[i][j] = (f32x4){0.f, 0.f, 0.f, 0.f};

  int i0 = wave * 32 + m15;
  int i1 = i0 + 16;
#pragma unroll
  for (int kc = 0; kc < K; kc += 32) {
    int c0 = (kc >> 3) + quad;
    short8v a0 = *(const short8v*)&As[i0 * K + ((c0 + i0) & CM) * 8];
    short8v a1 = *(const short8v*)&As[i1 * K + ((c0 + i1) & CM) * 8];
    short8v b[NT];
#pragma unroll
    for (int nt = 0; nt < NT; ++nt) {
      int nn = nt * 16 + m15;
      b[nt] = *(const short8v*)&Ws[nn * K + ((c0 + nn) & CM) * 8];
    }
#pragma unroll
    for (int nt = 0; nt < NT; ++nt) {
      acc[0][nt] = __builtin_amdgcn_mfma_f32_16x16x32_bf16(a0, b[nt], acc[0][nt], 0, 0, 0);
      acc[1][nt] = __builtin_amdgcn_mfma_f32_16x16x32_bf16(a1, b[nt], acc[1][nt], 0, 0, 0);
    }
  }

#pragma unroll
  for (int rt = 0; rt < 2; ++rt) {
    int rbase = blockM + wave * 32 + rt * 16 + quad * 4;
#pragma unroll
    for (int nt = 0; nt < NT; ++nt) {
      int colg = nt * 16 + m15;
      float bv = bias ? bias[colg] : 0.f;
#pragma unroll
      for (int r = 0; r < 4; ++r) {
        int row = rbase + r;
        if (row < n) {
          float v = acc[rt][nt][r] + bv;
          if (RELU) v = fmaxf(v, 0.f);
          C[(size_t)row * DOUT + colg] = f2bf(v);
        }
      }
    }
  }
}

// ---- fused L2 aggregate(+bias) -> F(f32) + column-sum (colmean) ----

__global__ __launch_bounds__(256) void k_aggpool(
    const unsigned short* __restrict__ X, float* __restrict__ F,
    const int* __restrict__ rowp, const int* __restrict__ col,
    const float* __restrict__ dinv, const float* __restrict__ bias,
    int n, double* __restrict__ gcsum) {
  int t = threadIdx.x;
  int g = t & 7, sub = t >> 3;   // 32 nodes per chunk, 8 lanes/node
  const ushort8v* x8 = (const ushort8v*)X;
  double csum[8];
#pragma unroll
  for (int j = 0; j < 8; ++j) csum[j] = 0.0;

  for (int base = blockIdx.x * 32; base < n; base += gridDim.x * 32) {
    int node = base + sub;
    if (node >= n) continue;
    float di = dinv[node];
    float acc[8];
    {
      ushort8v xs = x8[(size_t)node * 8 + g];
#pragma unroll
      for (int j = 0; j < 8; ++j) acc[j] = di * bf2f(xs[j]);
    }
    int e = rowp[node], e1 = rowp[node + 1];
    for (; e + 4 <= e1; e += 4) {
      int s0 = col[e], s1 = col[e + 1], s2 = col[e + 2], s3 = col[e + 3];
      float w0 = dinv[s0], w1 = dinv[s1], w2 = dinv[s2], w3 = dinv[s3];
      ushort8v v0 = x8[(size_t)s0 * 8 + g];
      ushort8v v1 = x8[(size_t)s1 * 8 + g];
      ushort8v v2 = x8[(size_t)s2 * 8 + g];
      ushort8v v3 = x8[(size_t)s3 * 8 + g];
#pragma unroll
      for (int j = 0; j < 8; ++j) {
        acc[j] += w0 * bf2f(v0[j]);
        acc[j] += w1 * bf2f(v1[j]);
        acc[j] += w2 * bf2f(v2[j]);
        acc[j] += w3 * bf2f(v3[j]);
      }
    }
    for (; e < e1; ++e) {
      int s = col[e];
      float w = dinv[s];
      ushort8v v = x8[(size_t)s * 8 + g];
#pragma unroll
      for (int j = 0; j < 8; ++j) acc[j] += w * bf2f(v[j]);
    }
    float r[8];
#pragma unroll
    for (int j = 0; j < 8; ++j) {
      r[j] = di * acc[j] + bias[g * 8 + j];
      csum[j] += (double)r[j];
    }
    float* op = F + (size_t)node * 64 + g * 8;
    *(float4*)(op + 0) = make_float4(r[0], r[1], r[2], r[3]);
    *(float4*)(op + 4) = make_float4(r[4], r[5], r[6], r[7]);
  }

  __shared__ double sd[256];
#pragma unroll 1
  for (int j = 0; j < 8; ++j) {
    sd[t] = csum[j];
    __syncthreads();
    for (int o = 128; o >= 8; o >>= 1) {
      if (t < o) sd[t] += sd[t + o];
      __syncthreads();
    }
    if (t < 8) atomicAdd(&gcsum[t * 8 + j], sd[t]);
    __syncthreads();
  }
}

// ---------------- hsum with inline gc ----------------

__global__ void k_hsum(const float* __restrict__ x, const double* __restrict__ gcsum,
                       const float* __restrict__ Wa, int n, double* __restrict__ hsum) {
  __shared__ float m[64], gcs[64];
  __shared__ double sd[256][4];
  int t = threadIdx.x;
  if (t < 64) m[t] = (float)(gcsum[t] / (double)n);
  __syncthreads();
  if (t < 64) {
    float s = 0.f;
    for (int d = 0; d < 64; ++d) s += m[d] * Wa[d * 64 + t];
    gcs[t] = tanhf(s);
  }
  __syncthreads();
  int g = t & 15, sub = t >> 4;
  float4 gcv = ((const float4*)gcs)[g];
  double a0 = 0, a1 = 0, a2 = 0, a3 = 0;
  for (int node = blockIdx.x * 16 + sub; node < n; node += gridDim.x * 16) {
    float4 xv = ((const float4*)x)[(size_t)node * 16 + g];
    float p = xv.x * gcv.x + xv.y * gcv.y + xv.z * gcv.z + xv.w * gcv.w;
    p += __shfl_xor(p, 1);
    p += __shfl_xor(p, 2);
    p += __shfl_xor(p, 4);
    p += __shfl_xor(p, 8);
    float att = 1.f / (1.f + expf(-p));
    a0 += (double)(att * xv.x); a1 += (double)(att * xv.y);
    a2 += (double)(att * xv.z); a3 += (double)(att * xv.w);
  }
  sd[t][0] = a0; sd[t][1] = a1; sd[t][2] = a2; sd[t][3] = a3;
  __syncthreads();
  if (t < 64) {
    int gg = t >> 2, j = t & 3;
    double tot = 0;
    for (int w = 0; w < 16; ++w) tot += sd[w * 16 + gg][j];
    atomicAdd(&hsum[t], tot);
  }
}

// ---------------- NTN + MLP ----------------

__global__ __launch_bounds__(256) void k_ntn(
    const double* __restrict__ hid, const double* __restrict__ hjd,
    const float* __restrict__ Wt, const float* __restrict__ Wm,
    const float* __restrict__ bn, float* __restrict__ z) {
  __shared__ float hi[64], hj[64], red[256];
  int b = blockIdx.x, t = threadIdx.x;
  if (t < 64) hi[t] = (float)hid[t];
  else if (t < 128) hj[t - 64] = (float)hjd[t - 64];
  __syncthreads();
  int r = t >> 2, c0 = (t & 3) * 16;
  const float* wr = Wt + ((size_t)b * 64 + r) * 64 + c0;
  float p = 0.f;
#pragma unroll
  for (int c = 0; c < 16; ++c) p += wr[c] * hj[c0 + c];
  p *= hi[r];
  if (t < 128) p += Wm[b * 128 + t] * (t < 64 ? hi[t] : hj[t - 64]);
  red[t] = p; __syncthreads();
  for (int o = 128; o > 0; o >>= 1) {
    if (t < o) red[t] += red[t + o];
    __syncthreads();
  }
  if (t == 0) z[b] = tanhf(red[0] + bn[b]);
}

__global__ void k_mlp(const float* __restrict__ z16,
                      const float* __restrict__ w0, const float* __restrict__ b0,
                      const float* __restrict__ w1, const float* __restrict__ b1,
                      const float* __restrict__ w2, const float* __restrict__ b2,
                      const float* __restrict__ w3, const float* __restrict__ b3,
                      const float* __restrict__ sw, const float* __restrict__ sb,
                      float* __restrict__ out) {
  __shared__ float z[16], u[32], v[16], w[8], q[4];
  int t = threadIdx.x;
  if (t < 16) z[t] = z16[t];
  __syncthreads();
  if (t < 32) {
    float s = b0[t];
    for (int i = 0; i < 16; ++i) s += z[i] * w0[i * 32 + t];
    u[t] = fmaxf(s, 0.f);
  }
  __syncthreads();
  if (t < 16) {
    float s = b1[t];
    for (int i = 0; i < 32; ++i) s += u[i] * w1[i * 16 + t];
    v[t] = fmaxf(s, 0.f);
  }
  __syncthreads();
  if (t < 8) {
    float s = b2[t];
    for (int i = 0; i < 16; ++i) s += v[i] * w2[i * 8 + t];
    w[t] = fmaxf(s, 0.f);
  }
  __syncthreads();
  if (t < 4) {
    float s = b3[t];
    for (int i = 0; i < 8; ++i) s += w[i] * w3[i * 4 + t];
    q[t] = fmaxf(s, 0.f);
  }
  __syncthreads();
  if (t == 0) {
    float s = sb[0];
    for (int i = 0; i < 4; ++i) s += q[i] * sw[i];
    out[0] = s;
  }
}

// ---------------- launch ----------------

extern "C" void kernel_launch(void* const* d_in, const int* in_sizes, int n_in,
                              void* d_out, int out_size, void* d_ws, size_t ws_size,
                              hipStream_t stream) {
  const float* x_i = (const float*)d_in[0];
  const int*   ei  = (const int*)d_in[1];
  const float* x_j = (const float*)d_in[2];
  const int*   ej  = (const int*)d_in[3];
  const float* cw0 = (const float*)d_in[4];  const float* cb0 = (const float*)d_in[5];
  const float* cw1 = (const float*)d_in[6];  const float* cb1 = (const float*)d_in[7];
  const float* cw2 = (const float*)d_in[8];  const float* cb2 = (const float*)d_in[9];
  const float* aw  = (const float*)d_in[10];
  const float* wt  = (const float*)d_in[11]; const float* wm  = (const float*)d_in[12];
  const float* bn  = (const float*)d_in[13];
  const float* m0w = (const float*)d_in[14]; const float* m0b = (const float*)d_in[15];
  const float* m1w = (const float*)d_in[16]; const float* m1b = (const float*)d_in[17];
  const float* m2w = (const float*)d_in[18]; const float* m2b = (const float*)d_in[19];
  const float* m3w = (const float*)d_in[20]; const float* m3b = (const float*)d_in[21];
  const float* sw  = (const float*)d_in[22]; const float* sb  = (const float*)d_in[23];

  int N = in_sizes[0] / 64;
  int E = in_sizes[1] / 2;

  char* p = (char*)d_ws;
  auto alloc = [&](size_t b) -> void* {
    void* r = (void*)p;
    p += (b + 255) & ~(size_t)255;
    return r;
  };
  int*    rowp  = (int*)alloc((size_t)(N + 1) * 4);
  int*    col   = (int*)alloc((size_t)E * 4);
  float*  dinv  = (float*)alloc((size_t)N * 4);
  int*    bucketCnt = (int*)alloc(256 * 4);
  int*    bstart    = (int*)alloc(257 * 4);
  int*    gcur      = (int*)alloc(256 * 4);
  double* gcsum = (double*)alloc(64 * 8);
  double* hsum  = (double*)alloc(128 * 8);
  float*  zbuf  = (float*)alloc(16 * 4);
  unsigned short* w0p = (unsigned short*)alloc(64 * 128 * 2);
  unsigned short* w1p = (unsigned short*)alloc(128 * 128 * 2);
  unsigned short* w2p = (unsigned short*)alloc(128 * 64 * 2);
  char* S1 = (char*)alloc((size_t)N * 128 * 2);   // 25.6 MB
  char* S2 = (char*)alloc((size_t)N * 128 * 2);   // 25.6 MB

  hipMemsetAsync(hsum, 0, 128 * 8, stream);

  k_wprep<<<CDIV(64 * 128, 256), 256, 0, stream>>>(cw0, w0p, 64, 128);
  k_wprep<<<CDIV(128 * 128, 256), 256, 0, stream>>>(cw1, w1p, 128, 128);
  k_wprep<<<CDIV(128 * 64, 256), 256, 0, stream>>>(cw2, w2p, 128, 64);

  for (int g = 0; g < 2; ++g) {
    const float* X  = g ? x_j : x_i;
    const int* src  = g ? ej : ei;
    const int* dst  = src + E;
    double* hs      = hsum + g * 64;

    // CSR (bucketed, write-coalesced); part transient in S1
    int2* part = (int2*)S1;
    hipMemsetAsync(bucketCnt, 0, 256 * 4, stream);
    k_bcount<<<CDIV(E, 2048), 256, 0, stream>>>(dst, E, bucketCnt);
    k_bscan<<<1, 256, 0, stream>>>(bucketCnt, bstart, gcur, rowp, N, E, gcsum);
    k_part<<<CDIV(E, 4096), 256, 0, stream>>>(src, dst, E, gcur, part);
    k_build<<<256, 256, 0, stream>>>(part, bstart, rowp, col, dinv, N);

    unsigned short* xbf = (unsigned short*)S2;
    k_tobf<<<CDIV(N * 8, 256), 256, 0, stream>>>(X, xbf, N * 8);

    unsigned short* G0 = (unsigned short*)S1;   // N x 128 bf16
    unsigned short* G1 = (unsigned short*)S2;   // N x 128 bf16 (overwrites xbf)
    unsigned short* G2 = (unsigned short*)S1;   // N x 64 bf16 (overwrites G0)
    float* F = (float*)S2;                      // N x 64 f32 (overwrites G1)

    // L0: G0 = relu(agg(xbf) @ W0 + b0)   [fused]
    k_aggemm<64, 128, true><<<CDIV(N, 128), 256, 0, stream>>>(
        xbf, w0p, cb0, G0, rowp, col, dinv, N);
    // L1: G1 = relu(agg(G0) @ W1 + b1)    [fused]
    k_aggemm<128, 128, true><<<CDIV(N, 128), 256, 0, stream>>>(
        G0, w1p, cb1, G1, rowp, col, dinv, N);
    // L2: G2 = G1 @ W2; F = agg(G2) + b2 with fused column-sum
    k_mgemm<128, 64, false><<<CDIV(N, 128), 256, 0, stream>>>(G1, w2p, nullptr, G2, N);
    k_aggpool<<<1024, 256, 0, stream>>>(G2, F, rowp, col, dinv, cb2, N, gcsum);

    // attention pooling (gc inline)
    k_hsum<<<512, 256, 0, stream>>>(F, gcsum, aw, N, hs);
  }

  k_ntn<<<16, 256, 0, stream>>>(hsum, hsum + 64, wt, wm, bn, zbuf);
  k_mlp<<<1, 64, 0, stream>>>(zbuf, m0w, m0b, m1w, m1b, m2w, m2b, m3w, m3b,
                              sw, sb, (float*)d_out);
}

// Round 6
// 609.096 us; speedup vs baseline: 1.8546x; 1.8546x over previous
//
#include <hip/hip_runtime.h>
#include <cstdint>
#include <cstddef>

#define CDIV(a,b) (((a)+(b)-1)/(b))

typedef __attribute__((ext_vector_type(8))) unsigned short ushort8v;
typedef __attribute__((ext_vector_type(8))) short short8v;
typedef __attribute__((ext_vector_type(4))) float f32x4;

__device__ __forceinline__ float bf2f(unsigned short u) {
  return __uint_as_float(((unsigned)u) << 16);
}
__device__ __forceinline__ unsigned short f2bf(float f) {
  unsigned u = __float_as_uint(f);
  unsigned r = (u + 0x7fff + ((u >> 16) & 1)) >> 16;
  return (unsigned short)r;
}

// ---------------- bucketed CSR build (batched: blockIdx.y = graph) ----------------

__global__ __launch_bounds__(256) void k_bcount(const int* __restrict__ dst0,
                                                const int* __restrict__ dst1, int E,
                                                int* __restrict__ bucketCnt) {
  __shared__ int h[256];
  int g = blockIdx.y;
  const int* dst = g ? dst1 : dst0;
  int t = threadIdx.x;
  h[t] = 0;
  __syncthreads();
  int e0 = blockIdx.x * 2048, e1 = min(e0 + 2048, E);
  for (int e = e0 + t; e < e1; e += 256) atomicAdd(&h[dst[e] >> 9], 1);
  __syncthreads();
  if (h[t]) atomicAdd(&bucketCnt[g * 256 + t], h[t]);
}

__global__ void k_bscan(const int* __restrict__ bucketCnt, int* __restrict__ bstart,
                        int* __restrict__ gcur, int* __restrict__ rowp, int n, int E) {
  __shared__ int sh[256];
  int g = blockIdx.x;           // 2 blocks, one per graph
  int t = threadIdx.x;
  int v = bucketCnt[g * 256 + t];
  sh[t] = v; __syncthreads();
  for (int o = 1; o < 256; o <<= 1) {
    int x = (t >= o) ? sh[t - o] : 0;
    __syncthreads();
    sh[t] += x;
    __syncthreads();
  }
  int ex = sh[t] - v;
  bstart[g * 257 + t] = ex;
  gcur[g * 256 + t] = ex;
  if (t == 255) {
    bstart[g * 257 + 256] = E;
    if (g == 1) rowp[2 * n] = 2 * E;
  }
}

__global__ __launch_bounds__(256) void k_part(const int* __restrict__ src0,
                                              const int* __restrict__ dst0,
                                              const int* __restrict__ src1,
                                              const int* __restrict__ dst1,
                                              int E, int N,
                                              int* __restrict__ gcur, int2* __restrict__ part) {
  __shared__ int bcnt[256], bbase[256], bcur[256];
  int g = blockIdx.y;
  const int* src = g ? src1 : src0;
  const int* dst = g ? dst1 : dst0;
  int nodeOff = g * N;
  int t = threadIdx.x;
  int e0 = blockIdx.x * 4096, e1 = min(e0 + 4096, E);
  bcnt[t] = 0;
  __syncthreads();
  for (int e = e0 + t; e < e1; e += 256) atomicAdd(&bcnt[dst[e] >> 9], 1);
  __syncthreads();
  bbase[t] = bcnt[t] ? atomicAdd(&gcur[g * 256 + t], bcnt[t]) : 0;
  bcur[t] = 0;
  __syncthreads();
  int2* pg = part + (size_t)g * E;
  for (int e = e0 + t; e < e1; e += 256) {
    int d = dst[e], s = src[e];
    int b = d >> 9;
    int off = atomicAdd(&bcur[b], 1);
    pg[bbase[b] + off] = make_int2(s + nodeOff, d);   // src globalized, dst local
  }
}

__global__ __launch_bounds__(256) void k_build(const int2* __restrict__ part,
                                               const int* __restrict__ bstart,
                                               int* __restrict__ rowp, int* __restrict__ col,
                                               float* __restrict__ dinv, int n, int E) {
  __shared__ int cnt[512], off[512], tmp[256];
  int g = blockIdx.y;
  int b = blockIdx.x;
  int lo = b << 9;
  if (lo >= n) return;
  int t = threadIdx.x;
  int s0 = bstart[g * 257 + b], s1 = bstart[g * 257 + b + 1];
  const int2* pg = part + (size_t)g * E;
  cnt[t] = 0; cnt[t + 256] = 0;
  __syncthreads();
  for (int e = s0 + t; e < s1; e += 256) atomicAdd(&cnt[pg[e].y - lo], 1);
  __syncthreads();
  int a0 = cnt[2 * t], a1 = cnt[2 * t + 1];
  int ps = a0 + a1;
  tmp[t] = ps; __syncthreads();
  for (int o = 1; o < 256; o <<= 1) {
    int x = (t >= o) ? tmp[t - o] : 0;
    __syncthreads();
    tmp[t] += x;
    __syncthreads();
  }
  int ex = tmp[t] - ps;
  off[2 * t] = ex;
  off[2 * t + 1] = ex + a0;
  __syncthreads();
  for (int i = t; i < 512; i += 256) {
    int node = lo + i;
    if (node < n) {
      rowp[g * n + node] = g * E + s0 + off[i];
      dinv[g * n + node] = rsqrtf((float)(cnt[i] + 1));
    }
  }
  __syncthreads();
  for (int e = s0 + t; e < s1; e += 256) {
    int2 pr = pg[e];
    int p = atomicAdd(&off[pr.y - lo], 1);
    col[g * E + s0 + p] = pr.x;
  }
}

// ---------------- f32 -> bf16 convert (both graphs) ----------------

__global__ void k_tobf(const float* __restrict__ in0, const float* __restrict__ in1,
                       unsigned short* __restrict__ out, int n8half, int n8) {
  int i = blockIdx.x * blockDim.x + threadIdx.x;
  if (i < n8) {
    const float4* i4 = (i < n8half) ? (const float4*)in0 : (const float4*)in1;
    int ii = (i < n8half) ? i : i - n8half;
    float4 a = i4[2 * ii], b = i4[2 * ii + 1];
    ushort8v r;
    r[0] = f2bf(a.x); r[1] = f2bf(a.y); r[2] = f2bf(a.z); r[3] = f2bf(a.w);
    r[4] = f2bf(b.x); r[5] = f2bf(b.y); r[6] = f2bf(b.z); r[7] = f2bf(b.w);
    ((ushort8v*)out)[i] = r;
  }
}

// ---- W prep: bf16, transposed to [n][k], chunk-swizzled LDS image ----

__global__ void k_wprep(const float* __restrict__ W, unsigned short* __restrict__ out,
                        int K, int DOUT) {
  int id = blockIdx.x * blockDim.x + threadIdx.x;
  if (id < K * DOUT) {
    int k = id / DOUT, n = id % DOUT;
    int CM = (K >> 3) - 1;
    out[n * K + (((k >> 3) + n) & CM) * 8 + (k & 7)] = f2bf(W[id]);
  }
}

// -------- GCN aggregate (bf16 in): out[d] = dinv[d]*(sum dinv[s]*x[s] + dinv[d]*x[d]) --------

template<int D, bool OUTBF, bool ADD_BIAS>
__global__ __launch_bounds__(256) void k_agg(
    const unsigned short* __restrict__ xin, void* __restrict__ xout,
    const int* __restrict__ rowp, const int* __restrict__ col,
    const float* __restrict__ dinv, const float* __restrict__ bias, int n) {
  constexpr int G = D / 8;
  constexpr int NPB = 256 / G;
  int node = blockIdx.x * NPB + threadIdx.x / G;
  int g = threadIdx.x % G;
  if (node >= n) return;
  const ushort8v* x8 = (const ushort8v*)xin;
  float di = dinv[node];
  float acc[8];
  {
    ushort8v xs = x8[(size_t)node * G + g];
#pragma unroll
    for (int j = 0; j < 8; ++j) acc[j] = di * bf2f(xs[j]);
  }
  int e = rowp[node], e1 = rowp[node + 1];
  for (; e + 4 <= e1; e += 4) {
    int s0 = col[e], s1 = col[e + 1], s2 = col[e + 2], s3 = col[e + 3];
    float w0 = dinv[s0], w1 = dinv[s1], w2 = dinv[s2], w3 = dinv[s3];
    ushort8v v0 = x8[(size_t)s0 * G + g];
    ushort8v v1 = x8[(size_t)s1 * G + g];
    ushort8v v2 = x8[(size_t)s2 * G + g];
    ushort8v v3 = x8[(size_t)s3 * G + g];
#pragma unroll
    for (int j = 0; j < 8; ++j) {
      acc[j] += w0 * bf2f(v0[j]);
      acc[j] += w1 * bf2f(v1[j]);
      acc[j] += w2 * bf2f(v2[j]);
      acc[j] += w3 * bf2f(v3[j]);
    }
  }
  for (; e < e1; ++e) {
    int s = col[e];
    float w = dinv[s];
    ushort8v v = x8[(size_t)s * G + g];
#pragma unroll
    for (int j = 0; j < 8; ++j) acc[j] += w * bf2f(v[j]);
  }
  float r[8];
#pragma unroll
  for (int j = 0; j < 8; ++j) {
    r[j] = di * acc[j];
    if (ADD_BIAS) r[j] += bias[g * 8 + j];
  }
  if (OUTBF) {
    ushort8v o;
#pragma unroll
    for (int j = 0; j < 8; ++j) o[j] = f2bf(r[j]);
    ((ushort8v*)xout)[(size_t)node * G + g] = o;
  } else {
    float* op = (float*)xout + (size_t)node * D + g * 8;
    *(float4*)(op + 0) = make_float4(r[0], r[1], r[2], r[3]);
    *(float4*)(op + 4) = make_float4(r[4], r[5], r[6], r[7]);
  }
}

// ---------------- MFMA GEMM (bf16 in/out, f32 acc) ----------------

template<int K, int DOUT, bool RELU>
__global__ __launch_bounds__(256) void k_mgemm(
    const unsigned short* __restrict__ A, const unsigned short* __restrict__ Wp,
    const float* __restrict__ bias, unsigned short* __restrict__ C, int n) {
  constexpr int CPR = K / 8;
  constexpr int CM = CPR - 1;
  constexpr int NT = DOUT / 16;
  __shared__ unsigned short As[128 * K];
  __shared__ unsigned short Ws[DOUT * K];
  int t = threadIdx.x;
  int blockM = blockIdx.x * 128;

#pragma unroll
  for (int id = t; id < 128 * CPR; id += 256) {
    int r = id / CPR, c = id % CPR;
    int grow = blockM + r;
    ushort8v v = {0, 0, 0, 0, 0, 0, 0, 0};
    if (grow < n) v = ((const ushort8v*)A)[(size_t)grow * CPR + c];
    *(ushort8v*)&As[r * K + ((c + r) & CM) * 8] = v;
  }
#pragma unroll
  for (int id = t; id < DOUT * CPR; id += 256) {
    ((ushort8v*)Ws)[id] = ((const ushort8v*)Wp)[id];
  }
  __syncthreads();

  int lane = t & 63, wave = t >> 6;
  int m15 = lane & 15, quad = lane >> 4;
  f32x4 acc[2][NT];
#pragma unroll
  for (int i = 0; i < 2; ++i)
#pragma unroll
    for (int j = 0; j < NT; ++j) acc[i][j] = (f32x4){0.f, 0.f, 0.f, 0.f};

  int i0 = wave * 32 + m15;
  int i1 = i0 + 16;
#pragma unroll
  for (int kc = 0; kc < K; kc += 32) {
    int c0 = (kc >> 3) + quad;
    short8v a0 = *(const short8v*)&As[i0 * K + ((c0 + i0) & CM) * 8];
    short8v a1 = *(const short8v*)&As[i1 * K + ((c0 + i1) & CM) * 8];
    short8v b[NT];
#pragma unroll
    for (int nt = 0; nt < NT; ++nt) {
      int nn = nt * 16 + m15;
      b[nt] = *(const short8v*)&Ws[nn * K + ((c0 + nn) & CM) * 8];
    }
#pragma unroll
    for (int nt = 0; nt < NT; ++nt) {
      acc[0][nt] = __builtin_amdgcn_mfma_f32_16x16x32_bf16(a0, b[nt], acc[0][nt], 0, 0, 0);
      acc[1][nt] = __builtin_amdgcn_mfma_f32_16x16x32_bf16(a1, b[nt], acc[1][nt], 0, 0, 0);
    }
  }

#pragma unroll
  for (int rt = 0; rt < 2; ++rt) {
    int rbase = blockM + wave * 32 + rt * 16 + quad * 4;
#pragma unroll
    for (int nt = 0; nt < NT; ++nt) {
      int colg = nt * 16 + m15;
      float bv = bias ? bias[colg] : 0.f;
#pragma unroll
      for (int r = 0; r < 4; ++r) {
        int row = rbase + r;
        if (row < n) {
          float v = acc[rt][nt][r] + bv;
          if (RELU) v = fmaxf(v, 0.f);
          C[(size_t)row * DOUT + colg] = f2bf(v);
        }
      }
    }
  }
}

// ---------------- attention pooling (both graphs in one dispatch) ----------------

__global__ void k_colmean(const float* __restrict__ x, int N, int n2,
                          double* __restrict__ gcsum) {
  __shared__ double sd[256];
  int t = threadIdx.x;
  int f = t & 63, rg = t >> 6;
  double acc0 = 0.0, acc1 = 0.0;
  for (int r = blockIdx.x * 4 + rg; r < n2; r += gridDim.x * 4) {
    double v = (double)x[(size_t)r * 64 + f];
    if (r < N) acc0 += v; else acc1 += v;
  }
#pragma unroll 1
  for (int j = 0; j < 2; ++j) {
    sd[t] = j ? acc1 : acc0;
    __syncthreads();
    if (t < 64) {
      double tot = sd[t] + sd[t + 64] + sd[t + 128] + sd[t + 192];
      if (tot != 0.0) atomicAdd(&gcsum[j * 64 + t], tot);
    }
    __syncthreads();
  }
}

__global__ void k_hsum(const float* __restrict__ x, const double* __restrict__ gcsum,
                       const float* __restrict__ Wa, int N, int n2,
                       double* __restrict__ hsum) {
  __shared__ float m[128], gcs[128];
  __shared__ double sd[256][4];
  int t = threadIdx.x;
  if (t < 128) m[t] = (float)(gcsum[t] / (double)N);
  __syncthreads();
  if (t < 128) {
    int gg = t >> 6, f = t & 63;
    float s = 0.f;
    for (int d = 0; d < 64; ++d) s += m[gg * 64 + d] * Wa[d * 64 + f];
    gcs[t] = tanhf(s);
  }
  __syncthreads();
  int g = t & 15, sub = t >> 4;
  float4 gcv0 = ((const float4*)gcs)[g];
  float4 gcv1 = ((const float4*)gcs)[16 + g];
  double a[2][4];
#pragma unroll
  for (int j = 0; j < 4; ++j) { a[0][j] = 0.0; a[1][j] = 0.0; }
  for (int node = blockIdx.x * 16 + sub; node < n2; node += gridDim.x * 16) {
    int gid = node >= N;
    float4 gcv = gid ? gcv1 : gcv0;
    float4 xv = ((const float4*)x)[(size_t)node * 16 + g];
    float p = xv.x * gcv.x + xv.y * gcv.y + xv.z * gcv.z + xv.w * gcv.w;
    p += __shfl_xor(p, 1);
    p += __shfl_xor(p, 2);
    p += __shfl_xor(p, 4);
    p += __shfl_xor(p, 8);
    float att = 1.f / (1.f + expf(-p));
    a[gid][0] += (double)(att * xv.x); a[gid][1] += (double)(att * xv.y);
    a[gid][2] += (double)(att * xv.z); a[gid][3] += (double)(att * xv.w);
  }
#pragma unroll 1
  for (int gid = 0; gid < 2; ++gid) {
    sd[t][0] = a[gid][0]; sd[t][1] = a[gid][1];
    sd[t][2] = a[gid][2]; sd[t][3] = a[gid][3];
    __syncthreads();
    if (t < 64) {
      int gg = t >> 2, j = t & 3;
      double tot = 0;
      for (int w = 0; w < 16; ++w) tot += sd[w * 16 + gg][j];
      if (tot != 0.0) atomicAdd(&hsum[gid * 64 + t], tot);
    }
    __syncthreads();
  }
}

// ---------------- NTN + MLP ----------------

__global__ __launch_bounds__(256) void k_ntn(
    const double* __restrict__ hid, const double* __restrict__ hjd,
    const float* __restrict__ Wt, const float* __restrict__ Wm,
    const float* __restrict__ bn, float* __restrict__ z) {
  __shared__ float hi[64], hj[64], red[256];
  int b = blockIdx.x, t = threadIdx.x;
  if (t < 64) hi[t] = (float)hid[t];
  else if (t < 128) hj[t - 64] = (float)hjd[t - 64];
  __syncthreads();
  int r = t >> 2, c0 = (t & 3) * 16;
  const float* wr = Wt + ((size_t)b * 64 + r) * 64 + c0;
  float p = 0.f;
#pragma unroll
  for (int c = 0; c < 16; ++c) p += wr[c] * hj[c0 + c];
  p *= hi[r];
  if (t < 128) p += Wm[b * 128 + t] * (t < 64 ? hi[t] : hj[t - 64]);
  red[t] = p; __syncthreads();
  for (int o = 128; o > 0; o >>= 1) {
    if (t < o) red[t] += red[t + o];
    __syncthreads();
  }
  if (t == 0) z[b] = tanhf(red[0] + bn[b]);
}

__global__ void k_mlp(const float* __restrict__ z16,
                      const float* __restrict__ w0, const float* __restrict__ b0,
                      const float* __restrict__ w1, const float* __restrict__ b1,
                      const float* __restrict__ w2, const float* __restrict__ b2,
                      const float* __restrict__ w3, const float* __restrict__ b3,
                      const float* __restrict__ sw, const float* __restrict__ sb,
                      float* __restrict__ out) {
  __shared__ float z[16], u[32], v[16], w[8], q[4];
  int t = threadIdx.x;
  if (t < 16) z[t] = z16[t];
  __syncthreads();
  if (t < 32) {
    float s = b0[t];
    for (int i = 0; i < 16; ++i) s += z[i] * w0[i * 32 + t];
    u[t] = fmaxf(s, 0.f);
  }
  __syncthreads();
  if (t < 16) {
    float s = b1[t];
    for (int i = 0; i < 32; ++i) s += u[i] * w1[i * 16 + t];
    v[t] = fmaxf(s, 0.f);
  }
  __syncthreads();
  if (t < 8) {
    float s = b2[t];
    for (int i = 0; i < 16; ++i) s += v[i] * w2[i * 8 + t];
    w[t] = fmaxf(s, 0.f);
  }
  __syncthreads();
  if (t < 4) {
    float s = b3[t];
    for (int i = 0; i < 8; ++i) s += w[i] * w3[i * 4 + t];
    q[t] = fmaxf(s, 0.f);
  }
  __syncthreads();
  if (t == 0) {
    float s = sb[0];
    for (int i = 0; i < 4; ++i) s += q[i] * sw[i];
    out[0] = s;
  }
}

// ---------------- launch ----------------

extern "C" void kernel_launch(void* const* d_in, const int* in_sizes, int n_in,
                              void* d_out, int out_size, void* d_ws, size_t ws_size,
                              hipStream_t stream) {
  const float* x_i = (const float*)d_in[0];
  const int*   ei  = (const int*)d_in[1];
  const float* x_j = (const float*)d_in[2];
  const int*   ej  = (const int*)d_in[3];
  const float* cw0 = (const float*)d_in[4];  const float* cb0 = (const float*)d_in[5];
  const float* cw1 = (const float*)d_in[6];  const float* cb1 = (const float*)d_in[7];
  const float* cw2 = (const float*)d_in[8];  const float* cb2 = (const float*)d_in[9];
  const float* aw  = (const float*)d_in[10];
  const float* wt  = (const float*)d_in[11]; const float* wm  = (const float*)d_in[12];
  const float* bn  = (const float*)d_in[13];
  const float* m0w = (const float*)d_in[14]; const float* m0b = (const float*)d_in[15];
  const float* m1w = (const float*)d_in[16]; const float* m1b = (const float*)d_in[17];
  const float* m2w = (const float*)d_in[18]; const float* m2b = (const float*)d_in[19];
  const float* m3w = (const float*)d_in[20]; const float* m3b = (const float*)d_in[21];
  const float* sw  = (const float*)d_in[22]; const float* sb  = (const float*)d_in[23];

  int N = in_sizes[0] / 64;
  int E = in_sizes[1] / 2;
  int N2 = 2 * N;

  char* p = (char*)d_ws;
  auto alloc = [&](size_t b) -> void* {
    void* r = (void*)p;
    p += (b + 255) & ~(size_t)255;
    return r;
  };
  // zero-region: bucketCnt | gcsum | hsum  (contiguous, one memset)
  int*    bucketCnt = (int*)alloc(512 * 4);          // 2048 B
  double* gcsum     = (double*)alloc(128 * 8);       // 1024 B
  double* hsum      = (double*)alloc(128 * 8);       // 1024 B
  int*    rowp  = (int*)alloc((size_t)(N2 + 1) * 4);
  int*    col   = (int*)alloc((size_t)2 * E * 4);
  float*  dinv  = (float*)alloc((size_t)N2 * 4);
  int*    bstart    = (int*)alloc(2 * 257 * 4);
  int*    gcur      = (int*)alloc(2 * 256 * 4);
  float*  zbuf  = (float*)alloc(16 * 4);
  unsigned short* w0p = (unsigned short*)alloc(64 * 128 * 2);
  unsigned short* w1p = (unsigned short*)alloc(128 * 128 * 2);
  unsigned short* w2p = (unsigned short*)alloc(128 * 64 * 2);
  char* S1 = (char*)alloc((size_t)N2 * 128 * 2);   // 51.2 MB
  char* S2 = (char*)alloc((size_t)N2 * 128 * 2);   // 51.2 MB

  hipMemsetAsync(bucketCnt, 0, 2048 + 1024 + 1024, stream);

  k_wprep<<<CDIV(64 * 128, 256), 256, 0, stream>>>(cw0, w0p, 64, 128);
  k_wprep<<<CDIV(128 * 128, 256), 256, 0, stream>>>(cw1, w1p, 128, 128);
  k_wprep<<<CDIV(128 * 64, 256), 256, 0, stream>>>(cw2, w2p, 128, 64);

  // ---- CSR for both graphs (part transient in S1: 2E*8 = 19.2 MB) ----
  int2* part = (int2*)S1;
  k_bcount<<<dim3(CDIV(E, 2048), 2), 256, 0, stream>>>(ei + E, ej + E, E, bucketCnt);
  k_bscan<<<2, 256, 0, stream>>>(bucketCnt, bstart, gcur, rowp, N, E);
  k_part<<<dim3(CDIV(E, 4096), 2), 256, 0, stream>>>(ei, ei + E, ej, ej + E, E, N, gcur, part);
  k_build<<<dim3(256, 2), 256, 0, stream>>>(part, bstart, rowp, col, dinv, N, E);

  // xbf = bf16([X_i; X_j]) in S2
  unsigned short* xbf = (unsigned short*)S2;
  k_tobf<<<CDIV(N2 * 8, 256), 256, 0, stream>>>(x_i, x_j, xbf, N * 8, N2 * 8);

  unsigned short* A0 = (unsigned short*)S1;   // N2 x 64 bf16 (overwrites part)
  unsigned short* G0 = (unsigned short*)S2;   // N2 x 128 bf16 (overwrites xbf)
  unsigned short* A1 = (unsigned short*)S1;   // N2 x 128 bf16
  unsigned short* G1 = (unsigned short*)S2;   // N2 x 128 bf16
  unsigned short* G2 = (unsigned short*)S1;   // N2 x 64 bf16
  float* F = (float*)S2;                      // N2 x 64 f32

  // L0
  k_agg<64, true, false><<<CDIV(N2, 32), 256, 0, stream>>>(xbf, A0, rowp, col, dinv, nullptr, N2);
  k_mgemm<64, 128, true><<<CDIV(N2, 128), 256, 0, stream>>>(A0, w0p, cb0, G0, N2);
  // L1
  k_agg<128, true, false><<<CDIV(N2, 16), 256, 0, stream>>>(G0, A1, rowp, col, dinv, nullptr, N2);
  k_mgemm<128, 128, true><<<CDIV(N2, 128), 256, 0, stream>>>(A1, w1p, cb1, G1, N2);
  // L2: GEMM then aggregate(+bias)
  k_mgemm<128, 64, false><<<CDIV(N2, 128), 256, 0, stream>>>(G1, w2p, nullptr, G2, N2);
  k_agg<64, false, true><<<CDIV(N2, 32), 256, 0, stream>>>(G2, F, rowp, col, dinv, cb2, N2);

  // attention pooling (both graphs, gc inline)
  k_colmean<<<1024, 256, 0, stream>>>(F, N, N2, gcsum);
  k_hsum<<<1024, 256, 0, stream>>>(F, gcsum, aw, N, N2, hsum);

  k_ntn<<<16, 256, 0, stream>>>(hsum, hsum + 64, wt, wm, bn, zbuf);
  k_mlp<<<1, 64, 0, stream>>>(zbuf, m0w, m0b, m1w, m1b, m2w, m2b, m3w, m3b,
                              sw, sb, (float*)d_out);
}